// Round 4
// baseline (424.386 us; speedup 1.0000x reference)
//
#include <hip/hip_runtime.h>

// LocallyConnected2D: B=16, H=W=64, CIN=32, 3x3 valid, F=64, OR=OC=62.
// R3: R2 fixed the 16x-redundant weight transport (224 -> ~142 us), but the
// main loop held only ONE weight load in flight per wave (blocking vmcnt(0)
// each iter). Now: fully-unrolled 18-trip loop with a named-register ring of
// depth 4 (wA..wD), load t+3 issued before compute t -> ~3 loads in flight
// per wave, waits become vmcnt(2)-style. Everything else identical to R2.

#define NB 16
#define CIN 32
#define F 64
#define OR 62
#define OC 62
#define KK 288
#define PADT 20       // patchT row stride (floats): conflict-free b128 reads
#define KPW 72        // k-rows per wave

__device__ __forceinline__ void fma4(float4& acc, float s, const float4 w) {
    acc.x = fmaf(s, w.x, acc.x);
    acc.y = fmaf(s, w.y, acc.y);
    acc.z = fmaf(s, w.z, acc.z);
    acc.w = fmaf(s, w.w, acc.w);
}

__global__ __launch_bounds__(256, 4)
void lc2d_kernel(const float* __restrict__ x,
                 const float* __restrict__ kern,
                 const float* __restrict__ bias,
                 float* __restrict__ out) {
    __shared__ __align__(16) float patchT[KK * PADT];   // 23040 B; reused as redtile

    const int p    = blockIdx.x;
    const int orr  = p / OC;
    const int occ  = p - orr * OC;
    const int tid  = threadIdx.x;
    const int lane = tid & 63;
    const int wv   = tid >> 6;
    const int q    = lane >> 4;
    const int fq   = lane & 15;

    // ---- stage patchT[k][b] (2-way bank aliasing on writes = free) ----
    for (int idx = tid; idx < NB * KK / 4; idx += 256) {
        const int b = idx & 15;
        const int k = (idx >> 4) << 2;
        const int i = k / 96;
        const int r = k - i * 96;
        const int j = r >> 5;
        const int c = r & 31;
        const float4 v = *reinterpret_cast<const float4*>(
            x + (((b * 64 + orr + i) * 64) + (occ + j)) * CIN + c);
        patchT[(k + 0) * PADT + b] = v.x;
        patchT[(k + 1) * PADT + b] = v.y;
        patchT[(k + 2) * PADT + b] = v.z;
        patchT[(k + 3) * PADT + b] = v.w;
    }
    __syncthreads();

    // ---- main loop: 18 iters, 1 KB distinct weights per wave-instr ----
    float4 acc[16];
#pragma unroll
    for (int u = 0; u < 16; ++u) acc[u] = make_float4(0.f, 0.f, 0.f, 0.f);

    const float* __restrict__ wp =
        kern + (size_t)p * (KK * F) + (KPW * wv + q) * F + 4 * fq;
    const float* __restrict__ ptbase = &patchT[(KPW * wv + q) * PADT];

    // register ring, depth 4: wA = iter t, wD = iter t+3 (being loaded)
    float4 wA = *reinterpret_cast<const float4*>(wp + 0 * (4 * F));
    float4 wB = *reinterpret_cast<const float4*>(wp + 1 * (4 * F));
    float4 wC = *reinterpret_cast<const float4*>(wp + 2 * (4 * F));
    float4 wD;

#pragma unroll
    for (int t = 0; t < 18; ++t) {
        if (t + 3 < 18)
            wD = *reinterpret_cast<const float4*>(wp + (t + 3) * (4 * F));
        const float* pt = ptbase + t * (4 * PADT);
        const float4 p0 = *reinterpret_cast<const float4*>(pt + 0);
        const float4 p1 = *reinterpret_cast<const float4*>(pt + 4);
        const float4 p2 = *reinterpret_cast<const float4*>(pt + 8);
        const float4 p3 = *reinterpret_cast<const float4*>(pt + 12);
        fma4(acc[0],  p0.x, wA); fma4(acc[1],  p0.y, wA);
        fma4(acc[2],  p0.z, wA); fma4(acc[3],  p0.w, wA);
        fma4(acc[4],  p1.x, wA); fma4(acc[5],  p1.y, wA);
        fma4(acc[6],  p1.z, wA); fma4(acc[7],  p1.w, wA);
        fma4(acc[8],  p2.x, wA); fma4(acc[9],  p2.y, wA);
        fma4(acc[10], p2.z, wA); fma4(acc[11], p2.w, wA);
        fma4(acc[12], p3.x, wA); fma4(acc[13], p3.y, wA);
        fma4(acc[14], p3.z, wA); fma4(acc[15], p3.w, wA);
        wA = wB; wB = wC; wC = wD;   // pure renaming after full unroll
    }

    // ---- intra-wave reduction across quarters ----
    const bool hi = (q >= 2);
    float4 acck[8];
#pragma unroll
    for (int s = 0; s < 8; ++s) {
        float4 send = hi ? acc[s] : acc[s + 8];
        float4 recv;
        recv.x = __shfl_xor(send.x, 32);
        recv.y = __shfl_xor(send.y, 32);
        recv.z = __shfl_xor(send.z, 32);
        recv.w = __shfl_xor(send.w, 32);
        const float4 mine = hi ? acc[s + 8] : acc[s];
        acck[s] = make_float4(mine.x + recv.x, mine.y + recv.y,
                              mine.z + recv.z, mine.w + recv.w);
    }
#pragma unroll
    for (int s = 0; s < 8; ++s) {
        acck[s].x += __shfl_xor(acck[s].x, 16);
        acck[s].y += __shfl_xor(acck[s].y, 16);
        acck[s].z += __shfl_xor(acck[s].z, 16);
        acck[s].w += __shfl_xor(acck[s].w, 16);
    }

    // ---- cross-wave reduction via LDS (reuse patchT) ----
    __syncthreads();
    {
        const int sbase = (q & 1) * 4;
        float* red = patchT + wv * 1024 + (4 * q) * F + 4 * fq;
#pragma unroll
        for (int u = 0; u < 4; ++u)
            *reinterpret_cast<float4*>(red + u * F) = acck[sbase + u];
    }
    __syncthreads();

    // ---- epilogue ----
    {
        const int fb = tid >> 4;
        const int ff = tid & 15;
        const float* r0 = patchT + fb * F + 4 * ff;
        float4 s0 = *reinterpret_cast<const float4*>(r0 + 0 * 1024);
        float4 s1 = *reinterpret_cast<const float4*>(r0 + 1 * 1024);
        float4 s2 = *reinterpret_cast<const float4*>(r0 + 2 * 1024);
        float4 s3 = *reinterpret_cast<const float4*>(r0 + 3 * 1024);
        const float4 bv = *reinterpret_cast<const float4*>(bias + p * F + 4 * ff);
        float4 o;
        o.x = s0.x + s1.x + s2.x + s3.x + bv.x;
        o.y = s0.y + s1.y + s2.y + s3.y + bv.y;
        o.z = s0.z + s1.z + s2.z + s3.z + bv.z;
        o.w = s0.w + s1.w + s2.w + s3.w + bv.w;
        float* op = out + ((size_t)fb * (OR * OC) + p) * F + 4 * ff;
        *reinterpret_cast<float4*>(op) = o;
    }
}

extern "C" void kernel_launch(void* const* d_in, const int* in_sizes, int n_in,
                              void* d_out, int out_size, void* d_ws, size_t ws_size,
                              hipStream_t stream) {
    const float* x    = (const float*)d_in[0];
    const float* kern = (const float*)d_in[1];
    const float* bias = (const float*)d_in[2];
    float* out = (float*)d_out;
    lc2d_kernel<<<dim3(OR * OC), dim3(256), 0, stream>>>(x, kern, bias, out);
}